// Round 1
// 772.433 us; speedup vs baseline: 1.1035x; 1.1035x over previous
//
#include <hip/hip_runtime.h>
#include <hip/hip_bf16.h>
#include <stdint.h>

// ---------------- types ----------------
typedef __bf16 bf16x8 __attribute__((ext_vector_type(8)));
typedef float f32x4 __attribute__((ext_vector_type(4)));
typedef unsigned short u16x8 __attribute__((ext_vector_type(8)));
typedef unsigned short u16x4 __attribute__((ext_vector_type(4)));

#define SCALE_LOG2E 0.18033688011112042f  // (1/sqrt(64)) * log2(e)

__device__ __forceinline__ unsigned short f2bf(float f) {
    union { float f; unsigned u; } v; v.f = f;
    unsigned r = v.u + 0x7FFFu + ((v.u >> 16) & 1u);
    return (unsigned short)(r >> 16);
}

__device__ __forceinline__ bf16x8 ld_frag(const unsigned short* p) {
    u16x8 u = *(const u16x8*)p;
    return __builtin_bit_cast(bf16x8, u);
}

// XOR swizzle for [64][64] u16 tiles (128B rows): flip 16B-slot bits by row&7.
// Keeps 16B alignment for 8-aligned cols; bijective within each row.
__device__ __forceinline__ int swz(int row, int col) {
    return (row * 64 + col) ^ ((row & 7) << 3);
}

// ---------------- W transpose + bf16 convert ----------------
__global__ void wt_kernel(const float* __restrict__ W, unsigned short* __restrict__ Wt) {
    int idx = blockIdx.x * blockDim.x + threadIdx.x;  // 0 .. 512*512-1
    int k = idx >> 9, n = idx & 511;
    Wt[n * 512 + k] = f2bf(W[idx]);
}

// ---------------- projection GEMM ----------------
// X: [8192][512] fp32, Wt: [512][512] bf16 (n-major), bias: [512]
// TRANS=0: Out[m][n] bf16 [8192][512]
// TRANS=1: Out = head-transposed [B=4][H=8][E=64][L=2048] bf16 (for V)
template <int TRANS>
__global__ __launch_bounds__(256)
void proj_kernel(const float* __restrict__ X, const unsigned short* __restrict__ Wt,
                 const float* __restrict__ bias, unsigned short* __restrict__ Out) {
    __shared__ unsigned short Xs[64 * 64];
    __shared__ unsigned short Ws[64 * 64];
    const int tid = threadIdx.x;
    const int wave = tid >> 6, lane = tid & 63;
    const int quad = lane >> 4, l16 = lane & 15;
    const int m0 = blockIdx.x * 64;
    const int n0 = blockIdx.y * 64;

    f32x4 acc[4] = {};

    for (int kc = 0; kc < 512; kc += 64) {
        // stage X tile (fp32 -> bf16), swizzled, packed 8B stores
        #pragma unroll
        for (int i = 0; i < 4; i++) {
            int e = tid + i * 256;          // group-of-4 index
            int row = e >> 4;
            int c4 = (e & 15) * 4;
            const float4 v = *(const float4*)&X[(size_t)(m0 + row) * 512 + kc + c4];
            u16x4 pk;
            pk[0] = f2bf(v.x); pk[1] = f2bf(v.y); pk[2] = f2bf(v.z); pk[3] = f2bf(v.w);
            *(u16x4*)&Xs[swz(row, c4)] = pk;
        }
        // stage Wt tile (already bf16): 16B vector copies, swizzled
        #pragma unroll
        for (int i = 0; i < 2; i++) {
            int e = tid + i * 256;          // group-of-8 index
            int row = e >> 3;
            int c8 = (e & 7) * 8;
            *(u16x8*)&Ws[swz(row, c8)] = *(const u16x8*)&Wt[(size_t)(n0 + row) * 512 + kc + c8];
        }
        __syncthreads();
        #pragma unroll
        for (int ks = 0; ks < 2; ks++) {
            bf16x8 a = ld_frag(&Xs[swz(wave * 16 + l16, ks * 32 + quad * 8)]);
            #pragma unroll
            for (int nn = 0; nn < 4; nn++) {
                bf16x8 b = ld_frag(&Ws[swz(nn * 16 + l16, ks * 32 + quad * 8)]);
                acc[nn] = __builtin_amdgcn_mfma_f32_16x16x32_bf16(a, b, acc[nn], 0, 0, 0);
            }
        }
        __syncthreads();
    }
    // epilogue: + bias, convert, store
    if (TRANS == 0) {
        #pragma unroll
        for (int nn = 0; nn < 4; nn++) {
            int n = n0 + nn * 16 + l16;
            float bv = bias[n];
            #pragma unroll
            for (int r = 0; r < 4; r++) {
                int m = m0 + wave * 16 + quad * 4 + r;
                Out[(size_t)m * 512 + n] = f2bf(acc[nn][r] + bv);
            }
        }
    } else {
        // head-transposed store: OutT[((b*8+h)*64 + e)*2048 + l], 4 consecutive l per thread
        const int bb = m0 >> 11;
        const int l0 = (m0 & 2047) + wave * 16 + quad * 4;
        #pragma unroll
        for (int nn = 0; nn < 4; nn++) {
            int n = n0 + nn * 16 + l16;
            float bv = bias[n];
            int hh = n >> 6, ee = n & 63;
            u16x4 pk;
            #pragma unroll
            for (int r = 0; r < 4; r++) pk[r] = f2bf(acc[nn][r] + bv);
            *(u16x4*)&Out[((size_t)(bb * 8 + hh) * 64 + ee) * 2048 + l0] = pk;
        }
    }
}

// ---------------- fused attention ----------------
// qb/kb: [8192][512] bf16; vtb: [B][H][64][2048] bf16 (pre-transposed)
// grid: (32 m-tiles, 8 heads, 4 batches), block 256 (4 waves, each 16 query rows)
__global__ __launch_bounds__(256)
void attn_kernel(const unsigned short* __restrict__ qb,
                 const unsigned short* __restrict__ kb,
                 const unsigned short* __restrict__ vtb,
                 float* __restrict__ out, float* __restrict__ attn) {
    __shared__ unsigned short Qs[64 * 64];
    __shared__ unsigned short Ks[64 * 64];
    __shared__ unsigned short Vt[64 * 64];   // Vt[e][j], staged directly (no scatter)
    __shared__ unsigned short Ps[64 * 64];

    const int tid = threadIdx.x;
    const int wave = tid >> 6, lane = tid & 63;
    const int quad = lane >> 4, l16 = lane & 15;
    const int mt = blockIdx.x;   // 0..31
    const int h  = blockIdx.y;   // 0..7
    const int b  = blockIdx.z;   // 0..3
    const int m0 = mt * 64;

    const unsigned short* Qg = qb + (size_t)b * 2048 * 512 + h * 64;
    const unsigned short* Kg = kb + (size_t)b * 2048 * 512 + h * 64;
    const unsigned short* Vg = vtb + (size_t)(b * 8 + h) * 64 * 2048;  // [e][l]

    // stage Q tile once (swizzled)
    #pragma unroll
    for (int i = 0; i < 2; i++) {
        int e = tid + i * 256;
        int row = e >> 3;
        int c8 = (e & 7) * 8;
        *(u16x8*)&Qs[swz(row, c8)] = *(const u16x8*)&Qg[(size_t)(m0 + row) * 512 + c8];
    }
    __syncthreads();

    // hoist Q fragments to registers (loop-invariant)
    bf16x8 qf[2];
    #pragma unroll
    for (int ks = 0; ks < 2; ks++)
        qf[ks] = ld_frag(&Qs[swz(wave * 16 + l16, ks * 32 + quad * 8)]);

    f32x4 o[4] = {};
    float lsum[4] = {0.f, 0.f, 0.f, 0.f};

    // ---- Pass 1: unnormalized O and row sums l ----
    for (int t = 0; t < 32; t++) {
        const int j0 = t * 64;
        // stage K tile (rows j, cols e), swizzled
        #pragma unroll
        for (int i = 0; i < 2; i++) {
            int e = tid + i * 256;
            int row = e >> 3;
            int c8 = (e & 7) * 8;
            *(u16x8*)&Ks[swz(row, c8)] = *(const u16x8*)&Kg[(size_t)(j0 + row) * 512 + c8];
        }
        // stage Vt tile (rows e, cols j) by straight vector copy from pre-transposed V
        #pragma unroll
        for (int i = 0; i < 2; i++) {
            int e = tid + i * 256;
            int row = e >> 3;          // e (head dim)
            int c8 = (e & 7) * 8;      // j-range
            *(u16x8*)&Vt[swz(row, c8)] = *(const u16x8*)&Vg[(size_t)row * 2048 + j0 + c8];
        }
        __syncthreads();
        // S = Q K^T for this 64x64 tile
        f32x4 s[4] = {};
        #pragma unroll
        for (int ks = 0; ks < 2; ks++) {
            #pragma unroll
            for (int nn = 0; nn < 4; nn++) {
                bf16x8 bf = ld_frag(&Ks[swz(nn * 16 + l16, ks * 32 + quad * 8)]);
                s[nn] = __builtin_amdgcn_mfma_f32_16x16x32_bf16(qf[ks], bf, s[nn], 0, 0, 0);
            }
        }
        // p = exp(s*scale), accumulate l, stash P (swizzled)
        #pragma unroll
        for (int nn = 0; nn < 4; nn++) {
            #pragma unroll
            for (int r = 0; r < 4; r++) {
                float p = exp2f(s[nn][r] * SCALE_LOG2E);
                lsum[r] += p;
                Ps[swz(wave * 16 + quad * 4 + r, nn * 16 + l16)] = f2bf(p);
            }
        }
        __syncthreads();   // Ps cross-lane visibility
        // O += P V
        #pragma unroll
        for (int ks = 0; ks < 2; ks++) {
            bf16x8 a = ld_frag(&Ps[swz(wave * 16 + l16, ks * 32 + quad * 8)]);
            #pragma unroll
            for (int nn = 0; nn < 4; nn++) {
                bf16x8 bf = ld_frag(&Vt[swz(nn * 16 + l16, ks * 32 + quad * 8)]);
                o[nn] = __builtin_amdgcn_mfma_f32_16x16x32_bf16(a, bf, o[nn], 0, 0, 0);
            }
        }
        __syncthreads();   // done reading Ks/Vt/Ps before restaging
    }

    // reduce l across the 16 lanes sharing each row
    #pragma unroll
    for (int r = 0; r < 4; r++) {
        float v = lsum[r];
        v += __shfl_xor(v, 1);
        v += __shfl_xor(v, 2);
        v += __shfl_xor(v, 4);
        v += __shfl_xor(v, 8);
        lsum[r] = v;
    }
    float inv[4];
    #pragma unroll
    for (int r = 0; r < 4; r++) inv[r] = 1.0f / lsum[r];

    // write out[b][m][h*64+e] = O/l
    float* og = out + (size_t)b * 2048 * 512 + h * 64;
    #pragma unroll
    for (int nn = 0; nn < 4; nn++) {
        #pragma unroll
        for (int r = 0; r < 4; r++) {
            int m = m0 + wave * 16 + quad * 4 + r;
            og[(size_t)m * 512 + nn * 16 + l16] = o[nn][r] * inv[r];
        }
    }

    // ---- Pass 2: recompute S, write normalized attn ----
    float* ag = attn + ((size_t)(b * 8 + h)) * 2048 * 2048;
    for (int t = 0; t < 32; t++) {
        const int j0 = t * 64;
        __syncthreads();   // prior tile's frag reads done before restage
        #pragma unroll
        for (int i = 0; i < 2; i++) {
            int e = tid + i * 256;
            int row = e >> 3;
            int c8 = (e & 7) * 8;
            *(u16x8*)&Ks[swz(row, c8)] = *(const u16x8*)&Kg[(size_t)(j0 + row) * 512 + c8];
        }
        __syncthreads();
        f32x4 s[4] = {};
        #pragma unroll
        for (int ks = 0; ks < 2; ks++) {
            #pragma unroll
            for (int nn = 0; nn < 4; nn++) {
                bf16x8 bf = ld_frag(&Ks[swz(nn * 16 + l16, ks * 32 + quad * 8)]);
                s[nn] = __builtin_amdgcn_mfma_f32_16x16x32_bf16(qf[ks], bf, s[nn], 0, 0, 0);
            }
        }
        #pragma unroll
        for (int nn = 0; nn < 4; nn++) {
            #pragma unroll
            for (int r = 0; r < 4; r++) {
                int m = m0 + wave * 16 + quad * 4 + r;
                float p = exp2f(s[nn][r] * SCALE_LOG2E) * inv[r];
                ag[(size_t)m * 2048 + j0 + nn * 16 + l16] = p;
            }
        }
    }
}

// ---------------- launcher ----------------
extern "C" void kernel_launch(void* const* d_in, const int* in_sizes, int n_in,
                              void* d_out, int out_size, void* d_ws, size_t ws_size,
                              hipStream_t stream) {
    const float* queries = (const float*)d_in[0];
    const float* keys    = (const float*)d_in[1];
    const float* values  = (const float*)d_in[2];
    const float* Wq = (const float*)d_in[3];
    const float* bq = (const float*)d_in[4];
    const float* Wk = (const float*)d_in[5];
    const float* bk = (const float*)d_in[6];
    const float* Wv = (const float*)d_in[7];
    const float* bv = (const float*)d_in[8];

    float* out  = (float*)d_out;                       // [4,2048,512]
    float* attn = out + (size_t)4 * 2048 * 512;        // [4,8,2048,2048]

    unsigned short* ws  = (unsigned short*)d_ws;
    unsigned short* Wtq = ws;                                // 512*512 bf16
    unsigned short* Wtk = Wtq + 512 * 512;
    unsigned short* Wtv = Wtk + 512 * 512;
    unsigned short* qb  = Wtv + 512 * 512;                   // 8192*512 bf16
    unsigned short* kb  = qb + (size_t)8192 * 512;
    unsigned short* vtb = kb + (size_t)8192 * 512;           // [4][8][64][2048] bf16

    dim3 bt(256);
    wt_kernel<<<dim3(512 * 512 / 256), bt, 0, stream>>>(Wq, Wtq);
    wt_kernel<<<dim3(512 * 512 / 256), bt, 0, stream>>>(Wk, Wtk);
    wt_kernel<<<dim3(512 * 512 / 256), bt, 0, stream>>>(Wv, Wtv);

    proj_kernel<0><<<dim3(128, 8), bt, 0, stream>>>(queries, Wtq, bq, qb);
    proj_kernel<0><<<dim3(128, 8), bt, 0, stream>>>(keys,    Wtk, bk, kb);
    proj_kernel<1><<<dim3(128, 8), bt, 0, stream>>>(values,  Wtv, bv, vtb);

    attn_kernel<<<dim3(32, 8, 4), bt, 0, stream>>>(qb, kb, vtb, out, attn);
}